// Round 8
// baseline (249.456 us; speedup 1.0000x reference)
//
#include <hip/hip_runtime.h>
#include <hip/hip_bf16.h>

#define N_ 256
#define D_ 64
#define H_ 4
#define DH_ 32
#define EQKV 384
#define EGATE 128
#define NPOS 65536
#define SCALE_F 0.17677669529663687f
#define BIG_NEG -3.402823466e38f
#define H_STRIDE 72    // K1 h tile stride (bf16)
#define PS 264         // k2 wave-private P slice stride (bf16): 528 B rows, 16B-aligned

typedef __attribute__((ext_vector_type(8))) short s16x8;
typedef __attribute__((ext_vector_type(4))) float f32x4;

// ws layout (bytes):
//   qk    bf16 [65536][256]           @ 0          (33554432 B)  q cols 0..127, k cols 128..255
//   v_t   bf16 [256][4][32][256]      @ 33554432   (16777216 B)  sigma-permuted j
//   bias  f32  [4][j=256][i=256]      @ 50331648   (1048576 B)   [h][j][i]
//   gate  f32  [65536][128]           @ 51380224   (33554432 B)

__device__ inline short bfbits(float x) {
    __hip_bfloat16 b = __float2bfloat16(x);
    return *reinterpret_cast<short*>(&b);
}
__device__ inline s16x8 cvt8(float4 a, float4 b) {
    s16x8 r;
    r[0] = bfbits(a.x); r[1] = bfbits(a.y); r[2] = bfbits(a.z); r[3] = bfbits(a.w);
    r[4] = bfbits(b.x); r[5] = bfbits(b.y); r[6] = bfbits(b.z); r[7] = bfbits(b.w);
    return r;
}

// ---------------- K1: layernorm + qkv + gate + bias (MFMA) ----------------
__global__ __launch_bounds__(512) void k1_ln_proj_mfma(
    const float* __restrict__ z, const float* __restrict__ ln_w, const float* __restrict__ ln_b,
    const float* __restrict__ w_qkv, const float* __restrict__ w_gate, const float* __restrict__ w_bias,
    __hip_bfloat16* __restrict__ qk_ws, __hip_bfloat16* __restrict__ v_t,
    float* __restrict__ gate_ws, float* __restrict__ bias_ws)
{
    __shared__ short h_bf[64 * H_STRIDE];
    const int t = threadIdx.x;
    const int wave = t >> 6, lane = t & 63;
    const int pos0 = blockIdx.x * 64;
    const int m = lane & 15, quad = lane >> 4;

    {
        const float lw = ln_w[lane], lb = ln_b[lane];
        const float wb0 = w_bias[lane], wb1 = w_bias[64 + lane],
                    wb2 = w_bias[128 + lane], wb3 = w_bias[192 + lane];
        for (int pp = 0; pp < 8; ++pp) {
            const int p = wave * 8 + pp;
            const float zv = z[(size_t)(pos0 + p) * 64 + lane];
            float s = zv, s2 = zv * zv;
            #pragma unroll
            for (int off = 32; off; off >>= 1) { s += __shfl_xor(s, off); s2 += __shfl_xor(s2, off); }
            const float mu = s * 0.015625f;
            const float var = s2 * 0.015625f - mu * mu;
            const float rs = rsqrtf(var + 1e-5f);
            const float hv = (zv - mu) * rs * lw + lb;
            h_bf[p * H_STRIDE + lane] = bfbits(hv);
            float b0 = hv * wb0, b1 = hv * wb1, b2 = hv * wb2, b3 = hv * wb3;
            #pragma unroll
            for (int off = 32; off; off >>= 1) {
                b0 += __shfl_xor(b0, off); b1 += __shfl_xor(b1, off);
                b2 += __shfl_xor(b2, off); b3 += __shfl_xor(b3, off);
            }
            if (lane < 4) {
                const int gpos = pos0 + p;
                const int gi = gpos >> 8, gj = gpos & 255;
                const float bv = lane == 0 ? b0 : lane == 1 ? b1 : lane == 2 ? b2 : b3;
                bias_ws[lane * NPOS + gj * 256 + gi] = bv;   // [h][j][i]
            }
        }
    }
    __syncthreads();

    const int colbase = wave * 64;
    s16x8 bfrag[4][2];
    #pragma unroll
    for (int nt = 0; nt < 4; ++nt) {
        const int col = colbase + nt * 16 + m;
        const float* wp = (col < EQKV) ? (w_qkv + (size_t)col * 64)
                                       : (w_gate + (size_t)(col - EQKV) * 64);
        #pragma unroll
        for (int kt = 0; kt < 2; ++kt) {
            const float4 w0 = *(const float4*)(wp + kt * 32 + quad * 8);
            const float4 w1 = *(const float4*)(wp + kt * 32 + quad * 8 + 4);
            bfrag[nt][kt] = cvt8(w0, w1);
        }
    }

    s16x8 afrag[4][2];
    #pragma unroll
    for (int mt = 0; mt < 4; ++mt)
        #pragma unroll
        for (int kt = 0; kt < 2; ++kt)
            afrag[mt][kt] = *(const s16x8*)(h_bf + (mt * 16 + m) * H_STRIDE + kt * 32 + quad * 8);

    f32x4 acc[4][4];
    #pragma unroll
    for (int mt = 0; mt < 4; ++mt)
        #pragma unroll
        for (int nt = 0; nt < 4; ++nt)
            acc[mt][nt] = (f32x4){0.f, 0.f, 0.f, 0.f};

    #pragma unroll
    for (int kt = 0; kt < 2; ++kt)
        #pragma unroll
        for (int mt = 0; mt < 4; ++mt)
            #pragma unroll
            for (int nt = 0; nt < 4; ++nt)
                acc[mt][nt] = __builtin_amdgcn_mfma_f32_16x16x32_bf16(
                    afrag[mt][kt], bfrag[nt][kt], acc[mt][nt], 0, 0, 0);

    if (colbase < 256) {
        // q,k columns -> qk_ws [pos][256]
        #pragma unroll
        for (int mt = 0; mt < 4; ++mt)
            #pragma unroll
            for (int nt = 0; nt < 4; ++nt) {
                const int c = colbase + nt * 16 + m;
                #pragma unroll
                for (int r = 0; r < 4; ++r) {
                    const int p = pos0 + mt * 16 + quad * 4 + r;
                    qk_ws[(size_t)p * 256 + c] = __float2bfloat16(acc[mt][nt][r]);
                }
            }
    } else if (colbase < EQKV) {
        // v columns -> v_t [n][h][d][sigma(j)]
        #pragma unroll
        for (int mt = 0; mt < 4; ++mt)
            #pragma unroll
            for (int nt = 0; nt < 4; ++nt) {
                const int e = colbase + nt * 16 + m - 256;
                const int hh = e >> 5, dd = e & 31;
                #pragma unroll
                for (int r = 0; r < 4; ++r) {
                    const int p = pos0 + mt * 16 + quad * 4 + r;
                    const int nn = p >> 8, j = p & 255;
                    const int csig = (j & 128) | ((j & 15) << 3) | ((j >> 4) & 7);
                    v_t[(size_t)((nn * 4 + hh) * 32 + dd) * 256 + csig] = __float2bfloat16(acc[mt][nt][r]);
                }
            }
    } else {
        #pragma unroll
        for (int mt = 0; mt < 4; ++mt)
            #pragma unroll
            for (int nt = 0; nt < 4; ++nt) {
                const int c = colbase - EQKV + nt * 16 + m;
                #pragma unroll
                for (int r = 0; r < 4; ++r) {
                    const int p = pos0 + mt * 16 + quad * 4 + r;
                    gate_ws[(size_t)p * EGATE + c] = 1.0f / (1.0f + __expf(-acc[mt][nt][r]));
                }
            }
    }
}

// ---------------- K2 v4: barrier-free fused attention + gate + out-proj ----------------
// grid 1024 = (n, ig); 256 threads = 4 waves; wave = mt (16 i-rows), owns all j and all h.
// No __syncthreads: P slice is wave-private; V^T read from global (sigma order).
__global__ __launch_bounds__(256, 4) void k2_attn_out_v4(
    const __hip_bfloat16* __restrict__ qk_ws, const __hip_bfloat16* __restrict__ v_t,
    const float* __restrict__ bias_ws, const int* __restrict__ mask,
    const float* __restrict__ gate_ws, const float* __restrict__ w_out,
    float* __restrict__ out)
{
    __shared__ short p_all[4 * 16 * PS];   // 33 KB: per-wave 16x264 slice

    const int bx = blockIdx.x;
    const int n = (bx & 7) | ((bx >> 5) << 3);   // XCD swizzle: same-n -> same XCD
    const int ig = (bx >> 3) & 3;
    const int i0 = ig * 64;
    const int t = threadIdx.x;
    const int wave = t >> 6, lane = t & 63;
    const int m = lane & 15, quad = lane >> 4;
    const int mt = wave;
    short* pSlice = p_all + wave * 16 * PS;

    // additive mask regs: j = tt16*16 + m
    float madd[16];
    #pragma unroll
    for (int tt16 = 0; tt16 < 16; ++tt16)
        madd[tt16] = (mask[n * 256 + tt16 * 16 + m] != 0) ? 0.0f : BIG_NEG;

    f32x4 acc_out[4];
    #pragma unroll
    for (int ot = 0; ot < 4; ++ot) acc_out[ot] = (f32x4){0.f, 0.f, 0.f, 0.f};

    for (int h = 0; h < 4; ++h) {
        const s16x8 afrag = *(const s16x8*)(qk_ws +
            (size_t)(n * 256 + i0 + mt * 16 + m) * 256 + h * 32 + quad * 8);

        float ls[4] = {0.f, 0.f, 0.f, 0.f};

        #pragma unroll
        for (int jh = 0; jh < 2; ++jh) {
            // S = Q K^T for this j-half
            s16x8 kf[8];
            #pragma unroll
            for (int tt = 0; tt < 8; ++tt)
                kf[tt] = *(const s16x8*)(qk_ws +
                    (size_t)(n * 256 + (jh * 8 + tt) * 16 + m) * 256 + 128 + h * 32 + quad * 8);
            f32x4 s[8];
            #pragma unroll
            for (int tt = 0; tt < 8; ++tt) {
                f32x4 z4 = {0.f, 0.f, 0.f, 0.f};
                s[tt] = __builtin_amdgcn_mfma_f32_16x16x32_bf16(afrag, kf[tt], z4, 0, 0, 0);
            }
            // scale + bias + mask, exp, row-sum partials
            #pragma unroll
            for (int tt = 0; tt < 8; ++tt) {
                const int j = jh * 128 + tt * 16 + m;
                const float ma = madd[jh * 8 + tt];
                const float4 b4 = *(const float4*)(bias_ws + (size_t)h * NPOS + j * 256
                                                   + i0 + mt * 16 + quad * 4);
                #pragma unroll
                for (int r = 0; r < 4; ++r) {
                    const float pv = __expf(s[tt][r] * SCALE_F + ((const float*)&b4)[r] + ma);
                    s[tt][r] = pv;
                    ls[r] += pv;
                }
            }
            // P -> wave-private LDS slice, b128, sigma order (col = jh*128 + m*8 + tt)
            #pragma unroll
            for (int r = 0; r < 4; ++r) {
                s16x8 pk;
                #pragma unroll
                for (int tt = 0; tt < 8; ++tt) pk[tt] = bfbits(s[tt][r]);
                *(s16x8*)(pSlice + (quad * 4 + r) * PS + jh * 128 + m * 8) = pk;
            }
        }

        // full row sums (16-lane reduce) -> 1/l
        #pragma unroll
        for (int r = 0; r < 4; ++r) {
            #pragma unroll
            for (int off = 1; off < 16; off <<= 1) ls[r] += __shfl_xor(ls[r], off);
        }

        // O = P V  (A from own slice, B from global v_t, both sigma-ordered)
        f32x4 o0 = {0.f, 0.f, 0.f, 0.f}, o1 = {0.f, 0.f, 0.f, 0.f};
        {
            const __hip_bfloat16* vb = v_t + (size_t)((n * 4 + h) * 32) * 256;
            #pragma unroll
            for (int kt = 0; kt < 8; ++kt) {
                const s16x8 pa = *(const s16x8*)(pSlice + m * PS + kt * 32 + quad * 8);
                const s16x8 b0 = *(const s16x8*)(vb + (size_t)m * 256 + kt * 32 + quad * 8);
                const s16x8 b1 = *(const s16x8*)(vb + (size_t)(16 + m) * 256 + kt * 32 + quad * 8);
                o0 = __builtin_amdgcn_mfma_f32_16x16x32_bf16(pa, b0, o0, 0, 0, 0);
                o1 = __builtin_amdgcn_mfma_f32_16x16x32_bf16(pa, b1, o1, 0, 0, 0);
            }
        }

        // X = (O/l)*gate -> slice cols 0..31 as [i][d] (natural d)
        #pragma unroll
        for (int r = 0; r < 4; ++r) {
            const float linv = 1.0f / ls[r];
            const size_t gbase = (size_t)(n * 256 + i0 + mt * 16 + quad * 4 + r) * 128 + h * 32;
            const float g0 = gate_ws[gbase + m];
            const float g1 = gate_ws[gbase + 16 + m];
            pSlice[(quad * 4 + r) * PS + m]      = bfbits(o0[r] * linv * g0);
            pSlice[(quad * 4 + r) * PS + 16 + m] = bfbits(o1[r] * linv * g1);
        }

        // out += X_h @ w_out_h^T  (K=32, 4 dout tiles)
        {
            const s16x8 xa = *(const s16x8*)(pSlice + m * PS + quad * 8);
            #pragma unroll
            for (int ot = 0; ot < 4; ++ot) {
                const float* wp = w_out + (size_t)(ot * 16 + m) * 128 + h * 32 + quad * 8;
                const s16x8 bw = cvt8(*(const float4*)wp, *(const float4*)(wp + 4));
                acc_out[ot] = __builtin_amdgcn_mfma_f32_16x16x32_bf16(xa, bw, acc_out[ot], 0, 0, 0);
            }
        }
    }

    // final store (coalesced per quad-row)
    #pragma unroll
    for (int ot = 0; ot < 4; ++ot)
        #pragma unroll
        for (int r = 0; r < 4; ++r) {
            const int p = n * 256 + i0 + mt * 16 + quad * 4 + r;
            out[(size_t)p * 64 + ot * 16 + m] = acc_out[ot][r];
        }
}

extern "C" void kernel_launch(void* const* d_in, const int* in_sizes, int n_in,
                              void* d_out, int out_size, void* d_ws, size_t ws_size,
                              hipStream_t stream) {
    const float* z      = (const float*)d_in[0];
    const int*   mask   = (const int*)d_in[1];
    const float* ln_w   = (const float*)d_in[2];
    const float* ln_b   = (const float*)d_in[3];
    const float* w_qkv  = (const float*)d_in[4];
    const float* w_bias = (const float*)d_in[5];
    const float* w_out  = (const float*)d_in[6];
    const float* w_gate = (const float*)d_in[7];
    float* out = (float*)d_out;

    char* ws = (char*)d_ws;
    __hip_bfloat16* qk_ws   = (__hip_bfloat16*)(ws);
    __hip_bfloat16* v_t     = (__hip_bfloat16*)(ws + 33554432);
    float*          bias_ws = (float*)(ws + 50331648);
    float*          gate_ws = (float*)(ws + 51380224);

    k1_ln_proj_mfma<<<1024, 512, 0, stream>>>(z, ln_w, ln_b, w_qkv, w_gate, w_bias,
                                              qk_ws, v_t, gate_ws, bias_ws);
    k2_attn_out_v4<<<1024, 256, 0, stream>>>(qk_ws, v_t, bias_ws, mask, gate_ws, w_out, out);
}